// Round 9
// baseline (162.309 us; speedup 1.0000x reference)
//
#include <hip/hip_runtime.h>
#include <math.h>

#define N_NODES  200000
#define N_EDGES  1250000
#define D        64
#define NGRAPH   128

#define BKT   196     // dst buckets: dst>>10
#define BSH   10
#define BCAP  8192    // capacity per bucket (mean 6400)

#define PARTB 306     // (N_EDGES+4095)/4096
#define CASTB 6250    // N_NODES*D/(256*8)
#define INITB 32      // (NGRAPH*D+255)/256

typedef unsigned int uint;
typedef unsigned short ushort;
typedef __attribute__((ext_vector_type(8))) short frag;     // 8 bf16
typedef __attribute__((ext_vector_type(4))) float f32x4;

__device__ inline uint bf1(float a) {
    uint u = __float_as_uint(a);
    return (u + 0x7fffu + ((u >> 16) & 1u)) >> 16;
}
__device__ inline float ubf_lo(uint u) { return __uint_as_float(u << 16); }
__device__ inline float ubf_hi(uint u) { return __uint_as_float(u & 0xffff0000u); }

__device__ inline void atomicMaxFloat(float* addr, float val) {
    if (val >= 0.f) atomicMax((int*)addr, __float_as_int(val));
    else            atomicMin((unsigned int*)addr, __float_as_uint(val));
}

#define ACC8(v)                                         \
    acc[0] += ubf_lo(v.x); acc[1] += ubf_hi(v.x);       \
    acc[2] += ubf_lo(v.y); acc[3] += ubf_hi(v.y);       \
    acc[4] += ubf_lo(v.z); acc[5] += ubf_hi(v.z);       \
    acc[6] += ubf_lo(v.w); acc[7] += ubf_hi(v.w);

// ========== fused: edge partition + x->bf16 cast + pool init ==========
__global__ __launch_bounds__(256) void k_part_cast(
    const int* __restrict__ srcs, const int* __restrict__ dsts,
    int* __restrict__ gcur, uint* __restrict__ recs,
    const float* __restrict__ x, ushort* __restrict__ xb,
    float* __restrict__ psum, float* __restrict__ pmax)
{
    const int bid = blockIdx.x;
    const int tid = threadIdx.x;
    if (bid < PARTB) {
        __shared__ int lhist[BKT];
        __shared__ int lbase[BKT];
        const long ebase = (long)bid * 4096;
        for (int i = tid; i < BKT; i += 256) lhist[i] = 0;
        __syncthreads();
        #pragma unroll
        for (int j = 0; j < 16; ++j) {
            long e = ebase + j * 256 + tid;
            if (e < N_EDGES) atomicAdd(&lhist[dsts[e] >> BSH], 1);
        }
        __syncthreads();
        for (int i = tid; i < BKT; i += 256) {
            int c = lhist[i];
            lbase[i] = c > 0 ? atomicAdd(&gcur[i], c) : 0;
            lhist[i] = 0;
        }
        __syncthreads();
        #pragma unroll
        for (int j = 0; j < 16; ++j) {
            long e = ebase + j * 256 + tid;
            if (e < N_EDGES) {
                int d = dsts[e];
                int s = srcs[e];
                int b = d >> BSH;
                int r = atomicAdd(&lhist[b], 1);
                recs[(long)b * BCAP + lbase[b] + r] = ((uint)(d & 1023) << 18) | (uint)s;
            }
        }
    } else if (bid < PARTB + CASTB) {
        long base = ((long)(bid - PARTB) * 256 + tid) * 8;
        float4 a = *(const float4*)(x + base);
        float4 b = *(const float4*)(x + base + 4);
        uint4 o;
        o.x = bf1(a.x) | (bf1(a.y) << 16);
        o.y = bf1(a.z) | (bf1(a.w) << 16);
        o.z = bf1(b.x) | (bf1(b.y) << 16);
        o.w = bf1(b.z) | (bf1(b.w) << 16);
        *(uint4*)(xb + base) = o;
    } else {
        int t = (bid - PARTB - CASTB) * 256 + tid;
        if (t < NGRAPH * D) {
            psum[t] = 0.f;
            pmax[t] = -INFINITY;
        }
    }
}

// ========== per-bucket CSR build ==========
__global__ __launch_bounds__(512) void k_fill2(const uint* __restrict__ recs,
                                               const int* __restrict__ gcur,
                                               int* __restrict__ csr,
                                               int2* __restrict__ rows)
{
    __shared__ uint srec[BCAP];
    __shared__ int  sdeg[1024];
    __shared__ int  soff[1024];
    __shared__ int  ss[512];
    const int b = blockIdx.x;
    const int tid = threadIdx.x;
    int cnt = gcur[b];
    if (cnt > BCAP) cnt = BCAP;
    for (int i = tid; i < 1024; i += 512) sdeg[i] = 0;
    __syncthreads();
    for (int i = tid; i < cnt; i += 512) {
        uint r = recs[(long)b * BCAP + i];
        srec[i] = r;
        atomicAdd(&sdeg[r >> 18], 1);
    }
    __syncthreads();
    int v0 = sdeg[2 * tid];
    int v1 = sdeg[2 * tid + 1];
    int ts = v0 + v1;
    ss[tid] = ts;
    __syncthreads();
    for (int off = 1; off < 512; off <<= 1) {
        int t = (tid >= off) ? ss[tid - off] : 0;
        __syncthreads();
        ss[tid] += t;
        __syncthreads();
    }
    int ex = ss[tid] - ts;
    soff[2 * tid]     = ex;
    soff[2 * tid + 1] = ex + v0;
    const int dbase = b << BSH;
    const int gbase = b * BCAP;
    int n0 = dbase + 2 * tid;
    if (n0 < N_NODES)     rows[n0]   = make_int2(gbase + ex,      gbase + ex + v0);
    if (n0 + 1 < N_NODES) rows[n0+1] = make_int2(gbase + ex + v0, gbase + ex + v0 + v1);
    __syncthreads();
    for (int i = tid; i < cnt; i += 512) {
        uint r = srec[i];
        int pos = atomicAdd(&soff[r >> 18], 1);
        csr[gbase + pos] = (int)(r & 0x3FFFFu);
    }
}

// ========== fused GIN conv: bf16 self+gather + MFMA MLP ==========
// MODE 0 (conv1): out = bf16(relu(mlp(z)))  -> OutB
// MODE 1 (conv2): out = mlp(z) pooled (sum/max per graph) -> psum/pmax atomics
template<int MODE>
__global__ __launch_bounds__(512, 4) void k_conv(
    const ushort* __restrict__ Gb,
    const int2* __restrict__ rows,
    const int* __restrict__ csr,
    const float* __restrict__ w1g, const float* __restrict__ b1g,
    const float* __restrict__ w2g, const float* __restrict__ b2g,
    ushort* __restrict__ OutB,
    const int* __restrict__ batch,
    float* __restrict__ psum, float* __restrict__ pmax)
{
    __shared__ ushort z_s[64 * 72];      // z / y bf16, row stride 72
    __shared__ ushort w_s[2][64 * 72];   // transposed weights [c][k]; reused as fp32 pool buf
    __shared__ float sb[2][64];
    __shared__ int sgid[64];
    const int tid = threadIdx.x;
    const long nbase = (long)blockIdx.x * 64;

    // ---- stage transposed bf16 weights ----
    {
        const int c = tid & 63;
        const int k0 = (tid >> 6) * 8;
        float v[8], w[8];
        #pragma unroll
        for (int j = 0; j < 8; ++j) {
            v[j] = w1g[(k0 + j) * D + c];
            w[j] = w2g[(k0 + j) * D + c];
        }
        uint4 p1, p2;
        p1.x = bf1(v[0]) | (bf1(v[1]) << 16);
        p1.y = bf1(v[2]) | (bf1(v[3]) << 16);
        p1.z = bf1(v[4]) | (bf1(v[5]) << 16);
        p1.w = bf1(v[6]) | (bf1(v[7]) << 16);
        p2.x = bf1(w[0]) | (bf1(w[1]) << 16);
        p2.y = bf1(w[2]) | (bf1(w[3]) << 16);
        p2.z = bf1(w[4]) | (bf1(w[5]) << 16);
        p2.w = bf1(w[6]) | (bf1(w[7]) << 16);
        *(uint4*)&w_s[0][c * 72 + k0] = p1;
        *(uint4*)&w_s[1][c * 72 + k0] = p2;
        if (tid < 64) sb[0][tid] = b1g[tid];
        else if (tid < 128) sb[1][tid - 64] = b2g[tid - 64];
    }

    // ---- gather: 8 threads/node, 8 feats each; 8-deep load unroll ----
    {
        const int nl = tid >> 3;
        const int fo = (tid & 7) * 8;
        const long n = nbase + nl;
        float acc[8];
        uint4 sv = *(const uint4*)(Gb + (n << 6) + fo);
        acc[0] = ubf_lo(sv.x); acc[1] = ubf_hi(sv.x);
        acc[2] = ubf_lo(sv.y); acc[3] = ubf_hi(sv.y);
        acc[4] = ubf_lo(sv.z); acc[5] = ubf_hi(sv.z);
        acc[6] = ubf_lo(sv.w); acc[7] = ubf_hi(sv.w);
        const int2 rw = rows[n];
        int i = rw.x;
        const int end = rw.y;
        for (; i + 7 < end; i += 8) {
            int s0 = csr[i],     s1 = csr[i + 1], s2 = csr[i + 2], s3 = csr[i + 3];
            int s4 = csr[i + 4], s5 = csr[i + 5], s6 = csr[i + 6], s7 = csr[i + 7];
            uint4 v0 = *(const uint4*)(Gb + ((long)s0 << 6) + fo);
            uint4 v1 = *(const uint4*)(Gb + ((long)s1 << 6) + fo);
            uint4 v2 = *(const uint4*)(Gb + ((long)s2 << 6) + fo);
            uint4 v3 = *(const uint4*)(Gb + ((long)s3 << 6) + fo);
            uint4 v4 = *(const uint4*)(Gb + ((long)s4 << 6) + fo);
            uint4 v5 = *(const uint4*)(Gb + ((long)s5 << 6) + fo);
            uint4 v6 = *(const uint4*)(Gb + ((long)s6 << 6) + fo);
            uint4 v7 = *(const uint4*)(Gb + ((long)s7 << 6) + fo);
            ACC8(v0); ACC8(v1); ACC8(v2); ACC8(v3);
            ACC8(v4); ACC8(v5); ACC8(v6); ACC8(v7);
        }
        for (; i + 1 < end; i += 2) {
            int s0 = csr[i], s1 = csr[i + 1];
            uint4 v0 = *(const uint4*)(Gb + ((long)s0 << 6) + fo);
            uint4 v1 = *(const uint4*)(Gb + ((long)s1 << 6) + fo);
            ACC8(v0); ACC8(v1);
        }
        if (i < end) {
            int s0 = csr[i];
            uint4 v0 = *(const uint4*)(Gb + ((long)s0 << 6) + fo);
            ACC8(v0);
        }
        uint4 o;
        o.x = bf1(acc[0]) | (bf1(acc[1]) << 16);
        o.y = bf1(acc[2]) | (bf1(acc[3]) << 16);
        o.z = bf1(acc[4]) | (bf1(acc[5]) << 16);
        o.w = bf1(acc[6]) | (bf1(acc[7]) << 16);
        *(uint4*)&z_s[nl * 72 + fo] = o;
    }
    __syncthreads();

    // ---- MFMA: 8 waves = 4 node-groups x 2 col-halves ----
    const int lane = tid & 63;
    const int wid = tid >> 6;
    const int rbase = (wid >> 1) * 16;
    const int cbase = (wid & 1) * 32;
    const int r16 = lane & 15;
    const int kg = lane >> 4;
    const int c0 = cbase + r16;
    const int c1 = cbase + 16 + r16;

    // layer 1
    frag a0 = *(const frag*)&z_s[(rbase + r16) * 72 + kg * 8];
    frag a1 = *(const frag*)&z_s[(rbase + r16) * 72 + 32 + kg * 8];
    frag b00 = *(const frag*)&w_s[0][c0 * 72 + kg * 8];
    frag b01 = *(const frag*)&w_s[0][c0 * 72 + 32 + kg * 8];
    frag b10 = *(const frag*)&w_s[0][c1 * 72 + kg * 8];
    frag b11 = *(const frag*)&w_s[0][c1 * 72 + 32 + kg * 8];
    f32x4 acc0, acc1;
    #pragma unroll
    for (int r = 0; r < 4; ++r) { acc0[r] = sb[0][c0]; acc1[r] = sb[0][c1]; }
    acc0 = __builtin_amdgcn_mfma_f32_16x16x32_bf16(a0, b00, acc0, 0, 0, 0);
    acc0 = __builtin_amdgcn_mfma_f32_16x16x32_bf16(a1, b01, acc0, 0, 0, 0);
    acc1 = __builtin_amdgcn_mfma_f32_16x16x32_bf16(a0, b10, acc1, 0, 0, 0);
    acc1 = __builtin_amdgcn_mfma_f32_16x16x32_bf16(a1, b11, acc1, 0, 0, 0);
    __syncthreads();

    // y = relu -> bf16 back into z_s
    #pragma unroll
    for (int r = 0; r < 4; ++r) {
        int row = rbase + kg * 4 + r;
        float y0 = acc0[r] > 0.f ? acc0[r] : 0.f;
        float y1 = acc1[r] > 0.f ? acc1[r] : 0.f;
        z_s[row * 72 + c0] = (ushort)bf1(y0);
        z_s[row * 72 + c1] = (ushort)bf1(y1);
    }
    __syncthreads();

    // layer 2
    a0 = *(const frag*)&z_s[(rbase + r16) * 72 + kg * 8];
    a1 = *(const frag*)&z_s[(rbase + r16) * 72 + 32 + kg * 8];
    b00 = *(const frag*)&w_s[1][c0 * 72 + kg * 8];
    b01 = *(const frag*)&w_s[1][c0 * 72 + 32 + kg * 8];
    b10 = *(const frag*)&w_s[1][c1 * 72 + kg * 8];
    b11 = *(const frag*)&w_s[1][c1 * 72 + 32 + kg * 8];
    #pragma unroll
    for (int r = 0; r < 4; ++r) { acc0[r] = sb[1][c0]; acc1[r] = sb[1][c1]; }
    acc0 = __builtin_amdgcn_mfma_f32_16x16x32_bf16(a0, b00, acc0, 0, 0, 0);
    acc0 = __builtin_amdgcn_mfma_f32_16x16x32_bf16(a1, b01, acc0, 0, 0, 0);
    acc1 = __builtin_amdgcn_mfma_f32_16x16x32_bf16(a0, b10, acc1, 0, 0, 0);
    acc1 = __builtin_amdgcn_mfma_f32_16x16x32_bf16(a1, b11, acc1, 0, 0, 0);

    if (MODE == 0) {
        #pragma unroll
        for (int r = 0; r < 4; ++r) {
            long node = nbase + rbase + kg * 4 + r;
            float v0 = acc0[r] > 0.f ? acc0[r] : 0.f;
            float v1 = acc1[r] > 0.f ? acc1[r] : 0.f;
            OutB[node * D + c0] = (ushort)bf1(v0);
            OutB[node * D + c1] = (ushort)bf1(v1);
        }
    } else {
        // conv2 epilogue: fused graph pooling (sum + max)
        __syncthreads();
        float* pbuf = (float*)&w_s[0][0];      // [64][66] fp32
        #pragma unroll
        for (int r = 0; r < 4; ++r) {
            int row = rbase + kg * 4 + r;
            pbuf[row * 66 + c0] = acc0[r];
            pbuf[row * 66 + c1] = acc1[r];
        }
        if (tid < 64) sgid[tid] = batch[nbase + tid];
        __syncthreads();
        const int g0 = sgid[0], g1 = sgid[63];
        float* rsum = (float*)&z_s[0];         // [8][64]
        float* rmax = rsum + 512;
        const int col = tid & 63;
        const int ch = tid >> 6;
        for (int g = g0; ; ++g) {
            float s = 0.f, m = -INFINITY;
            #pragma unroll
            for (int r = 0; r < 8; ++r) {
                int row = ch * 8 + r;
                if (sgid[row] == g) {
                    float v = pbuf[row * 66 + col];
                    s += v;
                    m = m > v ? m : v;
                }
            }
            rsum[ch * 64 + col] = s;
            rmax[ch * 64 + col] = m;
            __syncthreads();
            if (tid < 64) {
                float S = 0.f, M = -INFINITY;
                #pragma unroll
                for (int c = 0; c < 8; ++c) {
                    S += rsum[c * 64 + tid];
                    float mm = rmax[c * 64 + tid];
                    M = M > mm ? M : mm;
                }
                atomicAdd(&psum[g * 64 + tid], S);
                atomicMaxFloat(&pmax[g * 64 + tid], M);
            }
            if (g == g1) break;
            __syncthreads();
        }
    }
}

// ================= MLP head =================
__device__ inline float silu(float x) { return x / (1.f + expf(-x)); }

__global__ __launch_bounds__(128) void k_head(
    const float* __restrict__ psum, const float* __restrict__ pmax,
    const float* __restrict__ w0, const float* __restrict__ b0,
    const float* __restrict__ w1, const float* __restrict__ b1,
    const float* __restrict__ w2, const float* __restrict__ b2,
    const float* __restrict__ w3, const float* __restrict__ b3,
    const float* __restrict__ w4, const float* __restrict__ b4,
    float* __restrict__ out)
{
    __shared__ float bufA[128];
    __shared__ float bufB[128];
    int g = blockIdx.x, t = threadIdx.x;
    bufA[t] = (t < 64) ? psum[g * 64 + t] : pmax[g * 64 + (t - 64)];
    __syncthreads();
    {
        float a = b0[t];
        for (int k = 0; k < 128; ++k) a += bufA[k] * w0[k * 128 + t];
        bufB[t] = silu(a);
    }
    __syncthreads();
    if (t < 64) {
        float a = b1[t];
        for (int k = 0; k < 128; ++k) a += bufB[k] * w1[k * 64 + t];
        bufA[t] = silu(a);
    }
    __syncthreads();
    if (t < 32) {
        float a = b2[t];
        for (int k = 0; k < 64; ++k) a += bufA[k] * w2[k * 32 + t];
        bufB[t] = silu(a);
    }
    __syncthreads();
    if (t < 16) {
        float a = b3[t];
        for (int k = 0; k < 32; ++k) a += bufB[k] * w3[k * 16 + t];
        bufA[t] = silu(a);
    }
    __syncthreads();
    if (t == 0) {
        float a = b4[0];
        for (int k = 0; k < 16; ++k) a += bufA[k] * w4[k];
        out[g] = a;
    }
}

extern "C" void kernel_launch(void* const* d_in, const int* in_sizes, int n_in,
                              void* d_out, int out_size, void* d_ws, size_t ws_size,
                              hipStream_t stream) {
    const float* x     = (const float*)d_in[0];
    const int*   ei    = (const int*)d_in[1];
    const int*   batch = (const int*)d_in[2];
    const float* c1w1 = (const float*)d_in[3];
    const float* c1b1 = (const float*)d_in[4];
    const float* c1w2 = (const float*)d_in[5];
    const float* c1b2 = (const float*)d_in[6];
    const float* c2w1 = (const float*)d_in[7];
    const float* c2b1 = (const float*)d_in[8];
    const float* c2w2 = (const float*)d_in[9];
    const float* c2b2 = (const float*)d_in[10];
    const float* hw0 = (const float*)d_in[11];
    const float* hb0 = (const float*)d_in[12];
    const float* hw1 = (const float*)d_in[13];
    const float* hb1 = (const float*)d_in[14];
    const float* hw2 = (const float*)d_in[15];
    const float* hb2 = (const float*)d_in[16];
    const float* hw3 = (const float*)d_in[17];
    const float* hb3 = (const float*)d_in[18];
    const float* hw4 = (const float*)d_in[19];
    const float* hb4 = (const float*)d_in[20];

    const size_t NF = (size_t)N_NODES * D;
    ushort* xb   = (ushort*)d_ws;                       // 25.6 MB
    ushort* hb   = xb + NF;                             // 25.6 MB
    float*  psum = (float*)(hb + NF);                   // 32 KB
    float*  pmax = psum + NGRAPH * D;                   // 32 KB
    int* gcur    = (int*)(pmax + NGRAPH * D);           // 256
    int2* rows   = (int2*)(gcur + 256);                 // 200000 int2 (1.6 MB)
    int* csr     = (int*)(rows + N_NODES);              // BKT*BCAP (6.4 MB)
    uint* recs   = (uint*)(csr + BKT * BCAP);           // BKT*BCAP (6.4 MB)
    float* out   = (float*)d_out;

    const int* srcs = ei;
    const int* dsts = ei + N_EDGES;

    const int convBlocks = N_NODES / 64;                // 3125

    // 1. zero bucket counters
    hipMemsetAsync(gcur, 0, 256 * sizeof(int), stream);

    // 2. partition edges + bf16 cast of x + pool init
    k_part_cast<<<PARTB + CASTB + INITB, 256, 0, stream>>>(
        srcs, dsts, gcur, recs, x, xb, psum, pmax);

    // 3. bucket-local CSR build
    k_fill2<<<BKT, 512, 0, stream>>>(recs, gcur, csr, rows);

    // 4. conv1: self+gather from xb -> hb (bf16 only)
    k_conv<0><<<convBlocks, 512, 0, stream>>>(
        xb, rows, csr, c1w1, c1b1, c1w2, c1b2,
        hb, (const int*)nullptr, (float*)nullptr, (float*)nullptr);

    // 5. conv2: self+gather from hb -> fused pooling into psum/pmax
    k_conv<1><<<convBlocks, 512, 0, stream>>>(
        hb, rows, csr, c2w1, c2b1, c2w2, c2b2,
        (ushort*)nullptr, batch, psum, pmax);

    // 6. head
    k_head<<<NGRAPH, 128, 0, stream>>>(psum, pmax,
                                       hw0, hb0, hw1, hb1, hw2, hb2, hw3, hb3, hw4, hb4,
                                       out);
}

// Round 10
// 131.861 us; speedup vs baseline: 1.2309x; 1.2309x over previous
//
#include <hip/hip_runtime.h>
#include <math.h>

#define N_NODES  200000
#define N_EDGES  1250000
#define D        64
#define NGRAPH   128

#define BKT   196     // dst buckets: dst>>10
#define BSH   10
#define BCAP  8192    // capacity per bucket (mean 6400)

#define PARTB 306     // (N_EDGES+4095)/4096
#define CASTB 6250    // N_NODES*D/(256*8)
#define INITB 32      // (NGRAPH*D+255)/256

typedef unsigned int uint;
typedef unsigned short ushort;
typedef __attribute__((ext_vector_type(8))) short frag;     // 8 bf16
typedef __attribute__((ext_vector_type(4))) float f32x4;

__device__ inline uint bf1(float a) {
    uint u = __float_as_uint(a);
    return (u + 0x7fffu + ((u >> 16) & 1u)) >> 16;
}
__device__ inline float ubf_lo(uint u) { return __uint_as_float(u << 16); }
__device__ inline float ubf_hi(uint u) { return __uint_as_float(u & 0xffff0000u); }

__device__ inline void atomicMaxFloat(float* addr, float val) {
    if (val >= 0.f) atomicMax((int*)addr, __float_as_int(val));
    else            atomicMin((unsigned int*)addr, __float_as_uint(val));
}

#define ACC8(v)                                         \
    acc[0] += ubf_lo(v.x); acc[1] += ubf_hi(v.x);       \
    acc[2] += ubf_lo(v.y); acc[3] += ubf_hi(v.y);       \
    acc[4] += ubf_lo(v.z); acc[5] += ubf_hi(v.z);       \
    acc[6] += ubf_lo(v.w); acc[7] += ubf_hi(v.w);

// ========== fused: edge partition + x->bf16 cast + pool init ==========
// partition blocks register-stage their 16 edges/thread: one pass over global edge data
__global__ __launch_bounds__(256) void k_part_cast(
    const int* __restrict__ srcs, const int* __restrict__ dsts,
    int* __restrict__ gcur, uint* __restrict__ recs,
    const float* __restrict__ x, ushort* __restrict__ xb,
    float* __restrict__ psum, float* __restrict__ pmax)
{
    const int bid = blockIdx.x;
    const int tid = threadIdx.x;
    if (bid < PARTB) {
        __shared__ int lhist[BKT];
        __shared__ int lbase[BKT];
        const long ebase = (long)bid * 4096;
        int ds[16], ss[16];
        #pragma unroll
        for (int j = 0; j < 16; ++j) {
            long e = ebase + j * 256 + tid;
            if (e < N_EDGES) { ds[j] = dsts[e]; ss[j] = srcs[e]; }
            else ds[j] = -1;
        }
        for (int i = tid; i < BKT; i += 256) lhist[i] = 0;
        __syncthreads();
        #pragma unroll
        for (int j = 0; j < 16; ++j)
            if (ds[j] >= 0) atomicAdd(&lhist[ds[j] >> BSH], 1);
        __syncthreads();
        for (int i = tid; i < BKT; i += 256) {
            int c = lhist[i];
            lbase[i] = c > 0 ? atomicAdd(&gcur[i], c) : 0;
            lhist[i] = 0;
        }
        __syncthreads();
        #pragma unroll
        for (int j = 0; j < 16; ++j) {
            if (ds[j] >= 0) {
                int b = ds[j] >> BSH;
                int r = atomicAdd(&lhist[b], 1);
                recs[(long)b * BCAP + lbase[b] + r] =
                    ((uint)(ds[j] & 1023) << 18) | (uint)ss[j];
            }
        }
    } else if (bid < PARTB + CASTB) {
        long base = ((long)(bid - PARTB) * 256 + tid) * 8;
        float4 a = *(const float4*)(x + base);
        float4 b = *(const float4*)(x + base + 4);
        uint4 o;
        o.x = bf1(a.x) | (bf1(a.y) << 16);
        o.y = bf1(a.z) | (bf1(a.w) << 16);
        o.z = bf1(b.x) | (bf1(b.y) << 16);
        o.w = bf1(b.z) | (bf1(b.w) << 16);
        *(uint4*)(xb + base) = o;
    } else {
        int t = (bid - PARTB - CASTB) * 256 + tid;
        if (t < NGRAPH * D) {
            psum[t] = 0.f;
            pmax[t] = -INFINITY;
        }
    }
}

// ========== per-bucket CSR build ==========
__global__ __launch_bounds__(512) void k_fill2(const uint* __restrict__ recs,
                                               const int* __restrict__ gcur,
                                               int* __restrict__ csr,
                                               int2* __restrict__ rows)
{
    __shared__ uint srec[BCAP];
    __shared__ int  sdeg[1024];
    __shared__ int  soff[1024];
    __shared__ int  ss[512];
    const int b = blockIdx.x;
    const int tid = threadIdx.x;
    int cnt = gcur[b];
    if (cnt > BCAP) cnt = BCAP;
    for (int i = tid; i < 1024; i += 512) sdeg[i] = 0;
    __syncthreads();
    for (int i = tid; i < cnt; i += 512) {
        uint r = recs[(long)b * BCAP + i];
        srec[i] = r;
        atomicAdd(&sdeg[r >> 18], 1);
    }
    __syncthreads();
    int v0 = sdeg[2 * tid];
    int v1 = sdeg[2 * tid + 1];
    int ts = v0 + v1;
    ss[tid] = ts;
    __syncthreads();
    for (int off = 1; off < 512; off <<= 1) {
        int t = (tid >= off) ? ss[tid - off] : 0;
        __syncthreads();
        ss[tid] += t;
        __syncthreads();
    }
    int ex = ss[tid] - ts;
    soff[2 * tid]     = ex;
    soff[2 * tid + 1] = ex + v0;
    const int dbase = b << BSH;
    const int gbase = b * BCAP;
    int n0 = dbase + 2 * tid;
    if (n0 < N_NODES)     rows[n0]   = make_int2(gbase + ex,      gbase + ex + v0);
    if (n0 + 1 < N_NODES) rows[n0+1] = make_int2(gbase + ex + v0, gbase + ex + v0 + v1);
    __syncthreads();
    for (int i = tid; i < cnt; i += 512) {
        uint r = srec[i];
        int pos = atomicAdd(&soff[r >> 18], 1);
        csr[gbase + pos] = (int)(r & 0x3FFFFu);
    }
}

// ========== fused GIN conv: bf16 self+gather + MFMA MLP ==========
// MODE 0 (conv1): out = bf16(relu(mlp(z)))  -> OutB
// MODE 1 (conv2): out = mlp(z) pooled (sum/max per graph) -> psum/pmax atomics
template<int MODE>
__global__ __launch_bounds__(512, 8) void k_conv(
    const ushort* __restrict__ Gb,
    const int2* __restrict__ rows,
    const int* __restrict__ csr,
    const float* __restrict__ w1g, const float* __restrict__ b1g,
    const float* __restrict__ w2g, const float* __restrict__ b2g,
    ushort* __restrict__ OutB,
    const int* __restrict__ batch,
    float* __restrict__ psum, float* __restrict__ pmax)
{
    __shared__ ushort z_s[64 * 72];      // z / y bf16, row stride 72
    __shared__ ushort w_s[2][64 * 72];   // transposed weights [c][k]; reused as fp32 pool buf
    __shared__ float sb[2][64];
    __shared__ int sgid[64];
    const int tid = threadIdx.x;
    const long nbase = (long)blockIdx.x * 64;

    // ---- stage transposed bf16 weights ----
    {
        const int c = tid & 63;
        const int k0 = (tid >> 6) * 8;
        float v[8], w[8];
        #pragma unroll
        for (int j = 0; j < 8; ++j) {
            v[j] = w1g[(k0 + j) * D + c];
            w[j] = w2g[(k0 + j) * D + c];
        }
        uint4 p1, p2;
        p1.x = bf1(v[0]) | (bf1(v[1]) << 16);
        p1.y = bf1(v[2]) | (bf1(v[3]) << 16);
        p1.z = bf1(v[4]) | (bf1(v[5]) << 16);
        p1.w = bf1(v[6]) | (bf1(v[7]) << 16);
        p2.x = bf1(w[0]) | (bf1(w[1]) << 16);
        p2.y = bf1(w[2]) | (bf1(w[3]) << 16);
        p2.z = bf1(w[4]) | (bf1(w[5]) << 16);
        p2.w = bf1(w[6]) | (bf1(w[7]) << 16);
        *(uint4*)&w_s[0][c * 72 + k0] = p1;
        *(uint4*)&w_s[1][c * 72 + k0] = p2;
        if (tid < 64) sb[0][tid] = b1g[tid];
        else if (tid < 128) sb[1][tid - 64] = b2g[tid - 64];
    }

    // ---- gather: 8 threads/node, 8 feats each ----
    {
        const int nl = tid >> 3;
        const int fo = (tid & 7) * 8;
        const long n = nbase + nl;
        float acc[8];
        uint4 sv = *(const uint4*)(Gb + (n << 6) + fo);
        acc[0] = ubf_lo(sv.x); acc[1] = ubf_hi(sv.x);
        acc[2] = ubf_lo(sv.y); acc[3] = ubf_hi(sv.y);
        acc[4] = ubf_lo(sv.z); acc[5] = ubf_hi(sv.z);
        acc[6] = ubf_lo(sv.w); acc[7] = ubf_hi(sv.w);
        const int2 rw = rows[n];
        int i = rw.x;
        const int end = rw.y;
        for (; i + 7 < end; i += 8) {
            int s0 = csr[i],     s1 = csr[i + 1], s2 = csr[i + 2], s3 = csr[i + 3];
            int s4 = csr[i + 4], s5 = csr[i + 5], s6 = csr[i + 6], s7 = csr[i + 7];
            uint4 v0 = *(const uint4*)(Gb + ((long)s0 << 6) + fo);
            uint4 v1 = *(const uint4*)(Gb + ((long)s1 << 6) + fo);
            uint4 v2 = *(const uint4*)(Gb + ((long)s2 << 6) + fo);
            uint4 v3 = *(const uint4*)(Gb + ((long)s3 << 6) + fo);
            uint4 v4 = *(const uint4*)(Gb + ((long)s4 << 6) + fo);
            uint4 v5 = *(const uint4*)(Gb + ((long)s5 << 6) + fo);
            uint4 v6 = *(const uint4*)(Gb + ((long)s6 << 6) + fo);
            uint4 v7 = *(const uint4*)(Gb + ((long)s7 << 6) + fo);
            ACC8(v0); ACC8(v1); ACC8(v2); ACC8(v3);
            ACC8(v4); ACC8(v5); ACC8(v6); ACC8(v7);
        }
        for (; i + 1 < end; i += 2) {
            int s0 = csr[i], s1 = csr[i + 1];
            uint4 v0 = *(const uint4*)(Gb + ((long)s0 << 6) + fo);
            uint4 v1 = *(const uint4*)(Gb + ((long)s1 << 6) + fo);
            ACC8(v0); ACC8(v1);
        }
        if (i < end) {
            int s0 = csr[i];
            uint4 v0 = *(const uint4*)(Gb + ((long)s0 << 6) + fo);
            ACC8(v0);
        }
        uint4 o;
        o.x = bf1(acc[0]) | (bf1(acc[1]) << 16);
        o.y = bf1(acc[2]) | (bf1(acc[3]) << 16);
        o.z = bf1(acc[4]) | (bf1(acc[5]) << 16);
        o.w = bf1(acc[6]) | (bf1(acc[7]) << 16);
        *(uint4*)&z_s[nl * 72 + fo] = o;
    }
    __syncthreads();

    // ---- MFMA: 8 waves = 4 node-groups x 2 col-halves ----
    const int lane = tid & 63;
    const int wid = tid >> 6;
    const int rbase = (wid >> 1) * 16;
    const int cbase = (wid & 1) * 32;
    const int r16 = lane & 15;
    const int kg = lane >> 4;
    const int c0 = cbase + r16;
    const int c1 = cbase + 16 + r16;

    // layer 1
    frag a0 = *(const frag*)&z_s[(rbase + r16) * 72 + kg * 8];
    frag a1 = *(const frag*)&z_s[(rbase + r16) * 72 + 32 + kg * 8];
    frag b00 = *(const frag*)&w_s[0][c0 * 72 + kg * 8];
    frag b01 = *(const frag*)&w_s[0][c0 * 72 + 32 + kg * 8];
    frag b10 = *(const frag*)&w_s[0][c1 * 72 + kg * 8];
    frag b11 = *(const frag*)&w_s[0][c1 * 72 + 32 + kg * 8];
    f32x4 acc0, acc1;
    #pragma unroll
    for (int r = 0; r < 4; ++r) { acc0[r] = sb[0][c0]; acc1[r] = sb[0][c1]; }
    acc0 = __builtin_amdgcn_mfma_f32_16x16x32_bf16(a0, b00, acc0, 0, 0, 0);
    acc0 = __builtin_amdgcn_mfma_f32_16x16x32_bf16(a1, b01, acc0, 0, 0, 0);
    acc1 = __builtin_amdgcn_mfma_f32_16x16x32_bf16(a0, b10, acc1, 0, 0, 0);
    acc1 = __builtin_amdgcn_mfma_f32_16x16x32_bf16(a1, b11, acc1, 0, 0, 0);
    __syncthreads();

    // y = relu -> bf16 back into z_s
    #pragma unroll
    for (int r = 0; r < 4; ++r) {
        int row = rbase + kg * 4 + r;
        float y0 = acc0[r] > 0.f ? acc0[r] : 0.f;
        float y1 = acc1[r] > 0.f ? acc1[r] : 0.f;
        z_s[row * 72 + c0] = (ushort)bf1(y0);
        z_s[row * 72 + c1] = (ushort)bf1(y1);
    }
    __syncthreads();

    // layer 2
    a0 = *(const frag*)&z_s[(rbase + r16) * 72 + kg * 8];
    a1 = *(const frag*)&z_s[(rbase + r16) * 72 + 32 + kg * 8];
    b00 = *(const frag*)&w_s[1][c0 * 72 + kg * 8];
    b01 = *(const frag*)&w_s[1][c0 * 72 + 32 + kg * 8];
    b10 = *(const frag*)&w_s[1][c1 * 72 + kg * 8];
    b11 = *(const frag*)&w_s[1][c1 * 72 + 32 + kg * 8];
    #pragma unroll
    for (int r = 0; r < 4; ++r) { acc0[r] = sb[1][c0]; acc1[r] = sb[1][c1]; }
    acc0 = __builtin_amdgcn_mfma_f32_16x16x32_bf16(a0, b00, acc0, 0, 0, 0);
    acc0 = __builtin_amdgcn_mfma_f32_16x16x32_bf16(a1, b01, acc0, 0, 0, 0);
    acc1 = __builtin_amdgcn_mfma_f32_16x16x32_bf16(a0, b10, acc1, 0, 0, 0);
    acc1 = __builtin_amdgcn_mfma_f32_16x16x32_bf16(a1, b11, acc1, 0, 0, 0);

    if (MODE == 0) {
        #pragma unroll
        for (int r = 0; r < 4; ++r) {
            long node = nbase + rbase + kg * 4 + r;
            float v0 = acc0[r] > 0.f ? acc0[r] : 0.f;
            float v1 = acc1[r] > 0.f ? acc1[r] : 0.f;
            OutB[node * D + c0] = (ushort)bf1(v0);
            OutB[node * D + c1] = (ushort)bf1(v1);
        }
    } else {
        // conv2 epilogue: fused graph pooling (sum + max)
        __syncthreads();
        float* pbuf = (float*)&w_s[0][0];      // [64][66] fp32
        #pragma unroll
        for (int r = 0; r < 4; ++r) {
            int row = rbase + kg * 4 + r;
            pbuf[row * 66 + c0] = acc0[r];
            pbuf[row * 66 + c1] = acc1[r];
        }
        if (tid < 64) sgid[tid] = batch[nbase + tid];
        __syncthreads();
        const int g0 = sgid[0], g1 = sgid[63];
        float* rsum = (float*)&z_s[0];         // [8][64]
        float* rmax = rsum + 512;
        const int col = tid & 63;
        const int ch = tid >> 6;
        for (int g = g0; ; ++g) {
            float s = 0.f, m = -INFINITY;
            #pragma unroll
            for (int r = 0; r < 8; ++r) {
                int row = ch * 8 + r;
                if (sgid[row] == g) {
                    float v = pbuf[row * 66 + col];
                    s += v;
                    m = m > v ? m : v;
                }
            }
            rsum[ch * 64 + col] = s;
            rmax[ch * 64 + col] = m;
            __syncthreads();
            if (tid < 64) {
                float S = 0.f, M = -INFINITY;
                #pragma unroll
                for (int c = 0; c < 8; ++c) {
                    S += rsum[c * 64 + tid];
                    float mm = rmax[c * 64 + tid];
                    M = M > mm ? M : mm;
                }
                atomicAdd(&psum[g * 64 + tid], S);
                atomicMaxFloat(&pmax[g * 64 + tid], M);
            }
            if (g == g1) break;
            __syncthreads();
        }
    }
}

// ================= MLP head =================
__device__ inline float silu(float x) { return x / (1.f + expf(-x)); }

__global__ __launch_bounds__(128) void k_head(
    const float* __restrict__ psum, const float* __restrict__ pmax,
    const float* __restrict__ w0, const float* __restrict__ b0,
    const float* __restrict__ w1, const float* __restrict__ b1,
    const float* __restrict__ w2, const float* __restrict__ b2,
    const float* __restrict__ w3, const float* __restrict__ b3,
    const float* __restrict__ w4, const float* __restrict__ b4,
    float* __restrict__ out)
{
    __shared__ float bufA[128];
    __shared__ float bufB[128];
    int g = blockIdx.x, t = threadIdx.x;
    bufA[t] = (t < 64) ? psum[g * 64 + t] : pmax[g * 64 + (t - 64)];
    __syncthreads();
    {
        float a = b0[t];
        for (int k = 0; k < 128; ++k) a += bufA[k] * w0[k * 128 + t];
        bufB[t] = silu(a);
    }
    __syncthreads();
    if (t < 64) {
        float a = b1[t];
        for (int k = 0; k < 128; ++k) a += bufB[k] * w1[k * 64 + t];
        bufA[t] = silu(a);
    }
    __syncthreads();
    if (t < 32) {
        float a = b2[t];
        for (int k = 0; k < 64; ++k) a += bufA[k] * w2[k * 32 + t];
        bufB[t] = silu(a);
    }
    __syncthreads();
    if (t < 16) {
        float a = b3[t];
        for (int k = 0; k < 32; ++k) a += bufB[k] * w3[k * 16 + t];
        bufA[t] = silu(a);
    }
    __syncthreads();
    if (t == 0) {
        float a = b4[0];
        for (int k = 0; k < 16; ++k) a += bufA[k] * w4[k];
        out[g] = a;
    }
}

extern "C" void kernel_launch(void* const* d_in, const int* in_sizes, int n_in,
                              void* d_out, int out_size, void* d_ws, size_t ws_size,
                              hipStream_t stream) {
    const float* x     = (const float*)d_in[0];
    const int*   ei    = (const int*)d_in[1];
    const int*   batch = (const int*)d_in[2];
    const float* c1w1 = (const float*)d_in[3];
    const float* c1b1 = (const float*)d_in[4];
    const float* c1w2 = (const float*)d_in[5];
    const float* c1b2 = (const float*)d_in[6];
    const float* c2w1 = (const float*)d_in[7];
    const float* c2b1 = (const float*)d_in[8];
    const float* c2w2 = (const float*)d_in[9];
    const float* c2b2 = (const float*)d_in[10];
    const float* hw0 = (const float*)d_in[11];
    const float* hb0 = (const float*)d_in[12];
    const float* hw1 = (const float*)d_in[13];
    const float* hb1 = (const float*)d_in[14];
    const float* hw2 = (const float*)d_in[15];
    const float* hb2 = (const float*)d_in[16];
    const float* hw3 = (const float*)d_in[17];
    const float* hb3 = (const float*)d_in[18];
    const float* hw4 = (const float*)d_in[19];
    const float* hb4 = (const float*)d_in[20];

    const size_t NF = (size_t)N_NODES * D;
    ushort* xb   = (ushort*)d_ws;                       // 25.6 MB
    ushort* hb   = xb + NF;                             // 25.6 MB
    float*  psum = (float*)(hb + NF);                   // 32 KB
    float*  pmax = psum + NGRAPH * D;                   // 32 KB
    int* gcur    = (int*)(pmax + NGRAPH * D);           // 256
    int2* rows   = (int2*)(gcur + 256);                 // 200000 int2 (1.6 MB)
    int* csr     = (int*)(rows + N_NODES);              // BKT*BCAP (6.4 MB)
    uint* recs   = (uint*)(csr + BKT * BCAP);           // BKT*BCAP (6.4 MB)
    float* out   = (float*)d_out;

    const int* srcs = ei;
    const int* dsts = ei + N_EDGES;

    const int convBlocks = N_NODES / 64;                // 3125

    // 1. zero bucket counters
    hipMemsetAsync(gcur, 0, 256 * sizeof(int), stream);

    // 2. partition edges + bf16 cast of x + pool init
    k_part_cast<<<PARTB + CASTB + INITB, 256, 0, stream>>>(
        srcs, dsts, gcur, recs, x, xb, psum, pmax);

    // 3. bucket-local CSR build
    k_fill2<<<BKT, 512, 0, stream>>>(recs, gcur, csr, rows);

    // 4. conv1: self+gather from xb -> hb (bf16 only)
    k_conv<0><<<convBlocks, 512, 0, stream>>>(
        xb, rows, csr, c1w1, c1b1, c1w2, c1b2,
        hb, (const int*)nullptr, (float*)nullptr, (float*)nullptr);

    // 5. conv2: self+gather from hb -> fused pooling into psum/pmax
    k_conv<1><<<convBlocks, 512, 0, stream>>>(
        hb, rows, csr, c2w1, c2b1, c2w2, c2b2,
        (ushort*)nullptr, batch, psum, pmax);

    // 6. head
    k_head<<<NGRAPH, 128, 0, stream>>>(psum, pmax,
                                       hw0, hb0, hw1, hb1, hw2, hb2, hw3, hb3, hw4, hb4,
                                       out);
}